// Round 3
// baseline (172.815 us; speedup 1.0000x reference)
//
#include <hip/hip_runtime.h>

typedef __attribute__((ext_vector_type(8))) short short8;
typedef __attribute__((ext_vector_type(4))) float f32x4;

#define S_DIM 8192
#define H_DIM 4096
#define A_DIM 1024

__device__ __forceinline__ short f2bf(float x) {
  unsigned u = __float_as_uint(x);
  u += 0x7fffu + ((u >> 16) & 1u);   // round-to-nearest-even
  return (short)(u >> 16);
}

__device__ __forceinline__ float bf2f(short b) {
  return __uint_as_float(((unsigned)(unsigned short)b) << 16);
}

__device__ __forceinline__ void gload16(const void* g, void* l) {
  __builtin_amdgcn_global_load_lds(
      (const __attribute__((address_space(1))) void*)g,
      (__attribute__((address_space(3))) void*)l, 16, 0, 0);
}

// K1: comb[a] = hidden . W_w[a] + W_b[a] + U_b[a]   (one wave per row)
__global__ __launch_bounds__(256) void comb_kernel(const float* __restrict__ hidden,
                                                   const float* __restrict__ Ww,
                                                   const float* __restrict__ Wb,
                                                   const float* __restrict__ Ub,
                                                   float* __restrict__ comb) {
  const int wave = threadIdx.x >> 6;
  const int lane = threadIdx.x & 63;
  const int a = blockIdx.x * 4 + wave;
  const float* row = Ww + (size_t)a * H_DIM;
  float acc = 0.f;
  for (int k = lane * 4; k < H_DIM; k += 64 * 4) {
    float4 w = *(const float4*)(row + k);
    float4 h = *(const float4*)(hidden + k);
    acc += w.x * h.x + w.y * h.y + w.z * h.z + w.w * h.w;
  }
  #pragma unroll
  for (int mk = 1; mk < 64; mk <<= 1) acc += __shfl_xor(acc, mk);
  if (lane == 0) comb[a] = acc + Wb[a] + Ub[a];
}

// K0: fp32 -> bf16 bulk convert (n8 = elements/8)
__global__ __launch_bounds__(256) void cvt_kernel(const float* __restrict__ src,
                                                  unsigned short* __restrict__ dst,
                                                  int n8) {
  const int stride = gridDim.x * blockDim.x;
  for (int i = blockIdx.x * blockDim.x + threadIdx.x; i < n8; i += stride) {
    float4 a = ((const float4*)src)[(size_t)i * 2];
    float4 b = ((const float4*)src)[(size_t)i * 2 + 1];
    short8 o;
    o[0] = f2bf(a.x); o[1] = f2bf(a.y); o[2] = f2bf(a.z); o[3] = f2bf(a.w);
    o[4] = f2bf(b.x); o[5] = f2bf(b.y); o[6] = f2bf(b.z); o[7] = f2bf(b.w);
    ((short8*)dst)[i] = o;
  }
}

// K2: bf16 MFMA GEMM, K-split by 2 (blockIdx.z), m97 structure.
// Each block stores its f32 128x128 tile to partialC[kz] (no atomics).
__global__ __launch_bounds__(256) void gemm_kspl_kernel(
    const unsigned short* __restrict__ A,   // Ebf  [S][H]
    const unsigned short* __restrict__ B,   // Uwbf [A][H]
    float* __restrict__ partialC) {         // [2][S][A]
  __shared__ __align__(16) unsigned short sA[128 * 64];   // 16 KB
  __shared__ __align__(16) unsigned short sB[128 * 64];   // 16 KB

  const int tid  = threadIdx.x;
  const int lane = tid & 63;
  const int wave = tid >> 6;
  const int wm = wave >> 1, wn = wave & 1;
  const int m0 = blockIdx.x * 128;
  const int n0 = blockIdx.y * 128;
  const int k0 = blockIdx.z * (H_DIM / 2);

  const int srow = wave * 32 + (lane >> 3);
  const int scol = (lane & 7) * 8;
  const unsigned short* ga = A + (size_t)(m0 + srow) * H_DIM + k0 + scol;
  const unsigned short* gb = B + (size_t)(n0 + srow) * H_DIM + k0 + scol;

  #define STAGE(kt) do {                                                     \
    const unsigned short* pa_ = ga + (size_t)(kt) * 64;                      \
    const unsigned short* pb_ = gb + (size_t)(kt) * 64;                      \
    _Pragma("unroll")                                                        \
    for (int i_ = 0; i_ < 4; ++i_) {                                         \
      gload16(pa_ + (size_t)i_ * 8 * H_DIM, &sA[(wave * 4 + i_) * 512]);     \
      gload16(pb_ + (size_t)i_ * 8 * H_DIM, &sB[(wave * 4 + i_) * 512]);     \
    }                                                                        \
  } while (0)

  f32x4 acc[4][4];
  const f32x4 zero = {0.f, 0.f, 0.f, 0.f};
  #pragma unroll
  for (int i = 0; i < 4; ++i)
    #pragma unroll
    for (int j = 0; j < 4; ++j) acc[i][j] = zero;

  STAGE(0);

  const int NK = (H_DIM / 2) / 64;   // 32
  for (int kt = 0; kt < NK; ++kt) {
    __syncthreads();           // vmcnt drained -> tile kt resident

    short8 af[2][4], bfr[2][4];
    #pragma unroll
    for (int ks = 0; ks < 2; ++ks) {
      #pragma unroll
      for (int i = 0; i < 4; ++i)
        af[ks][i] = *(const short8*)&sA[(wm * 64 + i * 16 + (lane & 15)) * 64 + ks * 32 + (lane >> 4) * 8];
      #pragma unroll
      for (int j = 0; j < 4; ++j)
        bfr[ks][j] = *(const short8*)&sB[(wn * 64 + j * 16 + (lane & 15)) * 64 + ks * 32 + (lane >> 4) * 8];
    }
    __syncthreads();           // all reads done; safe to overwrite

    if (kt + 1 < NK) STAGE(kt + 1);   // in flight under MFMA

    #pragma unroll
    for (int ks = 0; ks < 2; ++ks)
      #pragma unroll
      for (int i = 0; i < 4; ++i)
        #pragma unroll
        for (int j = 0; j < 4; ++j)
          acc[i][j] = __builtin_amdgcn_mfma_f32_16x16x32_bf16(af[ks][i], bfr[ks][j], acc[ks ? i : i][j], 0, 0, 0);
  }
  #undef STAGE

  float* pc = partialC + (size_t)blockIdx.z * S_DIM * A_DIM;
  #pragma unroll
  for (int i = 0; i < 4; ++i) {
    #pragma unroll
    for (int r = 0; r < 4; ++r) {
      const int grow = m0 + wm * 64 + i * 16 + (lane >> 4) * 4 + r;
      float* prow = pc + (size_t)grow * A_DIM + n0 + wn * 64 + (lane & 15);
      #pragma unroll
      for (int j = 0; j < 4; ++j) prow[j * 16] = acc[i][j][r];
    }
  }
}

// K2b: scores[s] = sum_a Vw[a] * tanh(P0[s,a] + P1[s,a] + comb[a])
__global__ __launch_bounds__(256) void tanh_score_kernel(
    const float* __restrict__ P,       // [2][S][A]
    const float* __restrict__ comb,
    const float* __restrict__ Vw,
    float* __restrict__ scores) {
  const int lane = threadIdx.x & 63;
  const int wave = threadIdx.x >> 6;
  float4 vw[4], cb[4];
  #pragma unroll
  for (int c = 0; c < 4; ++c) {
    vw[c] = *(const float4*)&Vw[c * 256 + lane * 4];
    cb[c] = *(const float4*)&comb[c * 256 + lane * 4];
  }
  const float* P1 = P + (size_t)S_DIM * A_DIM;
  const int row0 = (blockIdx.x * 4 + wave) * 4;   // 512 blocks * 4 waves * 4 rows = 8192
  #pragma unroll
  for (int rr = 0; rr < 4; ++rr) {
    const int s = row0 + rr;
    const float* p0 = P  + (size_t)s * A_DIM;
    const float* p1 = P1 + (size_t)s * A_DIM;
    float acc = 0.f;
    #pragma unroll
    for (int c = 0; c < 4; ++c) {
      float4 x0 = *(const float4*)&p0[c * 256 + lane * 4];
      float4 x1 = *(const float4*)&p1[c * 256 + lane * 4];
      acc += vw[c].x * tanhf(x0.x + x1.x + cb[c].x);
      acc += vw[c].y * tanhf(x0.y + x1.y + cb[c].y);
      acc += vw[c].z * tanhf(x0.z + x1.z + cb[c].z);
      acc += vw[c].w * tanhf(x0.w + x1.w + cb[c].w);
    }
    #pragma unroll
    for (int mk = 1; mk < 64; mk <<= 1) acc += __shfl_xor(acc, mk);
    if (lane == 0) scores[s] = acc;
  }
}

// K3: softmax over 8192 scores -> attn (single block)
__global__ __launch_bounds__(1024) void softmax_kernel(const float* __restrict__ scores,
                                                       float* __restrict__ attn) {
  __shared__ float redm[16];
  __shared__ float reds[16];
  const int tid = threadIdx.x;
  const int lane = tid & 63, wid = tid >> 6;
  float v[8];
  float m = -3.0e38f;
  #pragma unroll
  for (int i = 0; i < 8; ++i) { v[i] = scores[i * 1024 + tid]; m = fmaxf(m, v[i]); }
  #pragma unroll
  for (int mk = 1; mk < 64; mk <<= 1) m = fmaxf(m, __shfl_xor(m, mk));
  if (lane == 0) redm[wid] = m;
  __syncthreads();
  float M = redm[0];
  #pragma unroll
  for (int j = 1; j < 16; ++j) M = fmaxf(M, redm[j]);
  float e[8]; float s = 0.f;
  #pragma unroll
  for (int i = 0; i < 8; ++i) { e[i] = __expf(v[i] - M); s += e[i]; }
  #pragma unroll
  for (int mk = 1; mk < 64; mk <<= 1) s += __shfl_xor(s, mk);
  if (lane == 0) reds[wid] = s;
  __syncthreads();
  float T = 0.f;
  #pragma unroll
  for (int j = 0; j < 16; ++j) T += reds[j];
  const float inv = 1.f / T;
  #pragma unroll
  for (int i = 0; i < 8; ++i) attn[i * 1024 + tid] = e[i] * inv;
}

// K4a: partial[y][h] = sum over 64-row chunk of attn[s]*Ebf[s][h], 8 cols/thread
__global__ __launch_bounds__(256) void context_bf_kernel(const unsigned short* __restrict__ Ebf,
                                                         const float* __restrict__ attn,
                                                         float* __restrict__ partial) {
  const int h0 = (blockIdx.x * 256 + threadIdx.x) * 8;
  const int s0 = blockIdx.y * 64;
  float acc[8] = {0.f, 0.f, 0.f, 0.f, 0.f, 0.f, 0.f, 0.f};
  for (int s = s0; s < s0 + 64; ++s) {
    const float w = attn[s];
    short8 e = *(const short8*)(Ebf + (size_t)s * H_DIM + h0);
    #pragma unroll
    for (int j = 0; j < 8; ++j) acc[j] += w * bf2f(e[j]);
  }
  float* p = partial + (size_t)blockIdx.y * H_DIM + h0;
  #pragma unroll
  for (int j = 0; j < 8; ++j) p[j] = acc[j];
}

// K4b: out[h] = sum_y partial[y][h]
__global__ __launch_bounds__(256) void context_reduce_kernel(const float* __restrict__ partial,
                                                             float* __restrict__ out) {
  const int h = blockIdx.x * 256 + threadIdx.x;
  float acc = 0.f;
  #pragma unroll 8
  for (int y = 0; y < 128; ++y) acc += partial[(size_t)y * H_DIM + h];
  out[h] = acc;
}

// ---------------- fallback (R2 fused-epilogue GEMM, needs only Ebf/Uwbf) -------------

__global__ __launch_bounds__(256) void gemm_score_bf_kernel(
    const unsigned short* __restrict__ A,
    const unsigned short* __restrict__ B,
    const float* __restrict__ comb,
    const float* __restrict__ Vw,
    float* __restrict__ scores) {
  __shared__ __align__(16) unsigned short sA[128 * 64];
  __shared__ __align__(16) unsigned short sB[128 * 64];
  const int tid  = threadIdx.x;
  const int lane = tid & 63;
  const int wave = tid >> 6;
  const int wm = wave >> 1, wn = wave & 1;
  const int m0 = blockIdx.x * 128;
  const int n0 = blockIdx.y * 128;
  const int srow = wave * 32 + (lane >> 3);
  const int scol = (lane & 7) * 8;
  const unsigned short* ga = A + (size_t)(m0 + srow) * H_DIM + scol;
  const unsigned short* gb = B + (size_t)(n0 + srow) * H_DIM + scol;
  #define STAGE(kt) do {                                                     \
    const unsigned short* pa_ = ga + (size_t)(kt) * 64;                      \
    const unsigned short* pb_ = gb + (size_t)(kt) * 64;                      \
    _Pragma("unroll")                                                        \
    for (int i_ = 0; i_ < 4; ++i_) {                                         \
      gload16(pa_ + (size_t)i_ * 8 * H_DIM, &sA[(wave * 4 + i_) * 512]);     \
      gload16(pb_ + (size_t)i_ * 8 * H_DIM, &sB[(wave * 4 + i_) * 512]);     \
    }                                                                        \
  } while (0)
  f32x4 acc[4][4];
  const f32x4 zero = {0.f, 0.f, 0.f, 0.f};
  #pragma unroll
  for (int i = 0; i < 4; ++i)
    #pragma unroll
    for (int j = 0; j < 4; ++j) acc[i][j] = zero;
  STAGE(0);
  const int NK = H_DIM / 64;
  for (int kt = 0; kt < NK; ++kt) {
    __syncthreads();
    short8 af[2][4], bfr[2][4];
    #pragma unroll
    for (int ks = 0; ks < 2; ++ks) {
      #pragma unroll
      for (int i = 0; i < 4; ++i)
        af[ks][i] = *(const short8*)&sA[(wm * 64 + i * 16 + (lane & 15)) * 64 + ks * 32 + (lane >> 4) * 8];
      #pragma unroll
      for (int j = 0; j < 4; ++j)
        bfr[ks][j] = *(const short8*)&sB[(wn * 64 + j * 16 + (lane & 15)) * 64 + ks * 32 + (lane >> 4) * 8];
    }
    __syncthreads();
    if (kt + 1 < NK) STAGE(kt + 1);
    #pragma unroll
    for (int ks = 0; ks < 2; ++ks)
      #pragma unroll
      for (int i = 0; i < 4; ++i)
        #pragma unroll
        for (int j = 0; j < 4; ++j)
          acc[i][j] = __builtin_amdgcn_mfma_f32_16x16x32_bf16(af[ks][i], bfr[ks][j], acc[i][j], 0, 0, 0);
  }
  #undef STAGE
  float vwv[4], cbv[4];
  #pragma unroll
  for (int j = 0; j < 4; ++j) {
    const int col = n0 + wn * 64 + j * 16 + (lane & 15);
    vwv[j] = Vw[col];
    cbv[j] = comb[col];
  }
  #pragma unroll
  for (int i = 0; i < 4; ++i) {
    #pragma unroll
    for (int r = 0; r < 4; ++r) {
      float s = 0.f;
      #pragma unroll
      for (int j = 0; j < 4; ++j)
        s += vwv[j] * tanhf(acc[i][j][r] + cbv[j]);
      s += __shfl_xor(s, 1);
      s += __shfl_xor(s, 2);
      s += __shfl_xor(s, 4);
      s += __shfl_xor(s, 8);
      if ((lane & 15) == 0) {
        const int grow = m0 + wm * 64 + i * 16 + (lane >> 4) * 4 + r;
        atomicAdd(&scores[grow], s);
      }
    }
  }
}

// ---------------- launch ----------------

extern "C" void kernel_launch(void* const* d_in, const int* in_sizes, int n_in,
                              void* d_out, int out_size, void* d_ws, size_t ws_size,
                              hipStream_t stream) {
  const float* E   = (const float*)d_in[0];
  const float* hid = (const float*)d_in[1];
  const float* Uw  = (const float*)d_in[2];
  const float* Ub  = (const float*)d_in[3];
  const float* Ww  = (const float*)d_in[4];
  const float* Wb  = (const float*)d_in[5];
  const float* Vw  = (const float*)d_in[6];
  // d_in[7] = V_b: softmax shift-invariant -> unused

  float* out    = (float*)d_out;
  float* ws     = (float*)d_ws;
  float* comb   = ws;                       // 1024 f32
  float* scores = ws + 1024;                // 8192 f32
  float* attn   = ws + 1024 + 8192;         // 8192 f32
  float* ctxp   = ws + 17408;               // 128*4096 f32
  const size_t CTXP = (size_t)128 * H_DIM;

  float* pC = ws + 17408 + CTXP;            // [2][S][A] f32 = 64 MB
  unsigned short* Ebf2  = (unsigned short*)(pC + 2 * (size_t)S_DIM * A_DIM);
  unsigned short* Uwbf2 = Ebf2 + (size_t)S_DIM * H_DIM;
  const size_t NEED2 = ((size_t)17408 + CTXP + 2 * (size_t)S_DIM * A_DIM) * 4
                     + ((size_t)S_DIM + A_DIM) * H_DIM * 2;

  unsigned short* Ebf1  = (unsigned short*)(ws + 17408 + CTXP);
  unsigned short* Uwbf1 = Ebf1 + (size_t)S_DIM * H_DIM;
  const size_t NEED1 = ((size_t)17408 + CTXP) * 4
                     + ((size_t)S_DIM + A_DIM) * H_DIM * 2;

  comb_kernel<<<A_DIM / 4, 256, 0, stream>>>(hid, Ww, Wb, Ub, comb);

  if (ws_size >= NEED2) {
    cvt_kernel<<<2048, 256, 0, stream>>>(E, Ebf2, (int)((size_t)S_DIM * H_DIM / 8));
    cvt_kernel<<<512, 256, 0, stream>>>(Uw, Uwbf2, (int)((size_t)A_DIM * H_DIM / 8));

    gemm_kspl_kernel<<<dim3(S_DIM / 128, A_DIM / 128, 2), 256, 0, stream>>>(Ebf2, Uwbf2, pC);
    tanh_score_kernel<<<512, 256, 0, stream>>>(pC, comb, Vw, scores);

    softmax_kernel<<<1, 1024, 0, stream>>>(scores, attn);

    context_bf_kernel<<<dim3(H_DIM / 2048, S_DIM / 64), 256, 0, stream>>>(Ebf2, attn, ctxp);
    context_reduce_kernel<<<H_DIM / 256, 256, 0, stream>>>(ctxp, out);
  } else {
    hipMemsetAsync(scores, 0, S_DIM * sizeof(float), stream);
    cvt_kernel<<<2048, 256, 0, stream>>>(E, Ebf1, (int)((size_t)S_DIM * H_DIM / 8));
    cvt_kernel<<<512, 256, 0, stream>>>(Uw, Uwbf1, (int)((size_t)A_DIM * H_DIM / 8));

    gemm_score_bf_kernel<<<dim3(S_DIM / 128, A_DIM / 128), 256, 0, stream>>>(Ebf1, Uwbf1, comb, Vw, scores);
    softmax_kernel<<<1, 1024, 0, stream>>>(scores, attn);
    context_bf_kernel<<<dim3(H_DIM / 2048, S_DIM / 64), 256, 0, stream>>>(Ebf1, attn, ctxp);
    context_reduce_kernel<<<H_DIM / 256, 256, 0, stream>>>(ctxp, out);
  }
}